// Round 1
// baseline (243.420 us; speedup 1.0000x reference)
//
#include <hip/hip_runtime.h>

// Edge-index generation for a B×H×W grid graph, reproducing the torch
// reference's ordering exactly:
//   per node i: [i,i], (i,left),(left,i) if x>0, (i,right),(right,i) if x<W-1,
//               (i,up),(up,i) if y>0, (i,down),(down,i) if y<H-1
//   then for the LAST node only: (i,sidx),(sidx,i) where sidx is the point
//   reflection through the grid center (loop-variable leak in the original).
// Output layout: out[0..E) = row 0 (sources), out[E..2E) = row 1 (targets).
//
// Offsets are closed-form prefix sums (no scan needed):
//   count(x,y)   = 1 + 2([x>0]+[x<W-1]+[y>0]+[y<H-1])
//   perBatch     = HW + 4H(W-1) + 4W(H-1)
//   rowsPrefix(y)= y*(3W + 4(W-1)) + 2W*max(y-1,0)        (valid for y<=H-1)
//   sumRow(x,y)  = x*(1+2*ry) + 2*(max(x-1,0) + x), ry=[y>0]+[y<H-1]

__global__ void EdgeIndexGenerator_12524124635757_kernel(
        const int* __restrict__ hptr, const int* __restrict__ wptr,
        int* __restrict__ out, long long outSize) {
    const int H = *hptr;
    const int W = *wptr;
    const long long E = outSize >> 1;
    const long long HW = (long long)H * W;
    const long long perBatch = HW + 4LL * H * (W - 1) + 4LL * W * (H - 1);
    const long long B = E / perBatch;
    const long long rem = E - B * perBatch;   // 2 => extra symmetric pair present
    const long long N = B * HW;

    long long i = (long long)blockIdx.x * blockDim.x + threadIdx.x;
    if (i >= N) return;

    const int b = (int)(i / HW);
    const int p = (int)(i - (long long)b * HW);
    const int x = p % W;
    const int y = p / W;

    const int ry = (y > 0) + (y < H - 1);
    const long long rowsPrefix =
        (long long)y * (3LL * W + 4LL * (W - 1)) + 2LL * W * (y > 0 ? y - 1 : 0);
    const long long sumRow =
        (long long)x * (1 + 2 * ry) + 2LL * ((x > 0 ? x - 1 : 0) + x);
    long long o = (long long)b * perBatch + rowsPrefix + sumRow;

    const int ii = (int)i;
    out[o] = ii; out[E + o] = ii; ++o;                 // self-loop
    if (x > 0) {
        const int n = ii - 1;
        out[o] = ii; out[E + o] = n; ++o;
        out[o] = n;  out[E + o] = ii; ++o;
    }
    if (x < W - 1) {
        const int n = ii + 1;
        out[o] = ii; out[E + o] = n; ++o;
        out[o] = n;  out[E + o] = ii; ++o;
    }
    if (y > 0) {
        const int n = ii - W;
        out[o] = ii; out[E + o] = n; ++o;
        out[o] = n;  out[E + o] = ii; ++o;
    }
    if (y < H - 1) {
        const int n = ii + W;
        out[o] = ii; out[E + o] = n; ++o;
        out[o] = n;  out[E + o] = ii; ++o;
    }

    // Last-node symmetric pair (appended at the very end of the edge list).
    if (rem == 2 && i == N - 1) {
        // cx=(W-1)/2, cy=(H-1)/2 as floats; 2*cx - x == (W-1) - x exactly.
        const int sx = (W - 1) - x;
        const int sy = (H - 1) - y;
        const int sidx = b * (int)HW + sy * W + sx;
        out[E - 2]     = ii;   out[E - 1]     = sidx;
        out[2 * E - 2] = sidx; out[2 * E - 1] = ii;
    }
}

extern "C" void kernel_launch(void* const* d_in, const int* in_sizes, int n_in,
                              void* d_out, int out_size, void* d_ws, size_t ws_size,
                              hipStream_t stream) {
    // d_in[0] = node_features (unused, only sizes matter)
    // d_in[1] = height (int scalar on device), d_in[2] = width
    const int* hptr = (const int*)d_in[1];
    const int* wptr = (const int*)d_in[2];
    int* out = (int*)d_out;

    const long long E = (long long)out_size >> 1;   // N <= E, so E threads cover all nodes
    const int threads = 256;
    const int blocks = (int)((E + threads - 1) / threads);
    EdgeIndexGenerator_12524124635757_kernel<<<blocks, threads, 0, stream>>>(
        hptr, wptr, out, (long long)out_size);
}

// Round 2
// 242.089 us; speedup vs baseline: 1.0055x; 1.0055x over previous
//
#include <hip/hip_runtime.h>

// Edge-index generation for a B×H×W grid graph, reproducing the torch
// reference's ordering exactly:
//   per node i: [i,i], (i,left),(left,i) if x>0, (i,right),(right,i) if x<W-1,
//               (i,up),(up,i) if y>0, (i,down),(down,i) if y<H-1
//   then for the LAST node only: (i,sidx),(sidx,i) — point reflection through
//   the grid center (loop-variable leak in the original torch code).
// Output layout: out[0..E) = row 0 (sources), out[E..2E) = row 1 (targets).
//
// Closed-form prefix sums (no scan):
//   count(x,y)   = 1 + 2([x>0]+[x<W-1]+[y>0]+[y<H-1])
//   perBatch     = HW + 4H(W-1) + 4W(H-1)
//   rowsPrefix(y)= y*(3W + 4(W-1)) + 2W*max(y-1,0)
//   sumRow(x,y)  = x*(1+2*ry) + 2*(max(x-1,0) + x),  ry=[y>0]+[y<H-1]
//
// All quantities fit in uint32 (E ~ 1.8M here; valid up to E < 2^31), so we
// use 32-bit arithmetic throughout — 64-bit runtime divides on gfx950 are
// ~300-cycle software sequences and were pure overhead in the previous rev.

__global__ void __launch_bounds__(256)
EdgeIndexGenerator_12524124635757_kernel(
        const int* __restrict__ hptr, const int* __restrict__ wptr,
        int* __restrict__ out, unsigned int outSize) {
    const unsigned int H = (unsigned int)*hptr;
    const unsigned int W = (unsigned int)*wptr;
    const unsigned int E = outSize >> 1;
    const unsigned int HW = H * W;
    const unsigned int perBatch = HW + 4u * H * (W - 1) + 4u * W * (H - 1);
    const unsigned int B = E / perBatch;
    const unsigned int rem = E - B * perBatch;  // 2 => symmetric pair appended
    const unsigned int N = B * HW;

    const unsigned int stride = gridDim.x * blockDim.x;
    for (unsigned int i = blockIdx.x * blockDim.x + threadIdx.x; i < N; i += stride) {
        const unsigned int b = i / HW;
        const unsigned int p = i - b * HW;
        const unsigned int x = p % W;
        const unsigned int y = p / W;

        const unsigned int ry = (y > 0) + (y < H - 1);
        const unsigned int rowsPrefix =
            y * (3u * W + 4u * (W - 1)) + 2u * W * (y > 0 ? y - 1 : 0);
        const unsigned int sumRow =
            x * (1u + 2u * ry) + 2u * ((x > 0 ? x - 1 : 0) + x);
        unsigned int o = b * perBatch + rowsPrefix + sumRow;

        const int ii = (int)i;
        out[o] = ii; out[E + o] = ii; ++o;              // self-loop
        if (x > 0) {
            const int n = ii - 1;
            out[o] = ii; out[E + o] = n; ++o;
            out[o] = n;  out[E + o] = ii; ++o;
        }
        if (x < W - 1) {
            const int n = ii + 1;
            out[o] = ii; out[E + o] = n; ++o;
            out[o] = n;  out[E + o] = ii; ++o;
        }
        if (y > 0) {
            const int n = ii - (int)W;
            out[o] = ii; out[E + o] = n; ++o;
            out[o] = n;  out[E + o] = ii; ++o;
        }
        if (y < H - 1) {
            const int n = ii + (int)W;
            out[o] = ii; out[E + o] = n; ++o;
            out[o] = n;  out[E + o] = ii; ++o;
        }

        // Last-node symmetric pair, appended at the very end of the edge list.
        // 2*cx - x == (W-1) - x exactly (cx=(W-1)/2), same for y.
        if (rem == 2 && i == N - 1) {
            const int sx = (int)(W - 1 - x);
            const int sy = (int)(H - 1 - y);
            const int sidx = (int)(b * HW) + sy * (int)W + sx;
            out[E - 2]     = ii;   out[E - 1]     = sidx;
            out[2 * E - 2] = sidx; out[2 * E - 1] = ii;
        }
    }
}

extern "C" void kernel_launch(void* const* d_in, const int* in_sizes, int n_in,
                              void* d_out, int out_size, void* d_ws, size_t ws_size,
                              hipStream_t stream) {
    // d_in[0] = node_features (unused — only its size matters, and only on device)
    // d_in[1] = height (device int scalar), d_in[2] = width (device int scalar)
    const int* hptr = (const int*)d_in[1];
    const int* wptr = (const int*)d_in[2];
    int* out = (int*)d_out;

    // N (worker count) is only derivable on-device (H,W live in device memory),
    // so use a grid-stride loop. 1024 blocks * 256 = 262144 threads covers the
    // benchmark shape (N = 200704) in a single stride iteration while keeping
    // every wave useful; larger N just strides.
    const int threads = 256;
    const int blocks = 1024;
    EdgeIndexGenerator_12524124635757_kernel<<<blocks, threads, 0, stream>>>(
        hptr, wptr, out, (unsigned int)out_size);
}